// Round 1
// baseline (18844.847 us; speedup 1.0000x reference)
//
#include <hip/hip_runtime.h>
#include <cstdint>
#include <cstddef>

#define CH 128
#define HH 40
#define WW 96
#define BB 64
#define HW (HH*WW)      // 3840
#define CHW ((size_t)CH*HW) // 491520

// ---------------------------------------------------------------------------
// Horizontal conv step (1x9 kernel along W, pad_w=4), rows rolled by hoff:
//   dst[b,co,h,w] = src[b,co,h,w] + 2*relu( sum_ci sum_t wgt[co,ci,t] *
//                                           src[b,ci,(h+hoff)%H, w+t-4] )
// Block: 256 threads, one block per (b,h). LDS: rolled row, all ci, +4 halo.
// ---------------------------------------------------------------------------
__global__ __launch_bounds__(256) void hconv_step(
    const float* __restrict__ src, const float* __restrict__ wgt,
    float* __restrict__ dst, int hoff)
{
    __shared__ float ld[CH][104];   // [ci][4 + 96 + 4], 53,248 B
    const int h   = blockIdx.x;
    const int b   = blockIdx.y;
    const int tid = threadIdx.x;
    const int hp  = (h + hoff) % HH;

    // stage rolled input row: src[b, ci, hp, 0..95] -> ld[ci][4..99]
    const float* srow = src + (size_t)b*CHW + (size_t)hp*WW;
    for (int idx = tid; idx < CH*24; idx += 256) {
        int ci = idx / 24;
        int j  = idx % 24;
        float4 v = *reinterpret_cast<const float4*>(srow + (size_t)ci*HW + j*4);
        *reinterpret_cast<float4*>(&ld[ci][4 + 4*j]) = v;
    }
    if (tid < CH) {
        *reinterpret_cast<float4*>(&ld[tid][0])   = make_float4(0.f,0.f,0.f,0.f);
        *reinterpret_cast<float4*>(&ld[tid][100]) = make_float4(0.f,0.f,0.f,0.f);
    }
    __syncthreads();

    const int tx  = tid & 7;    // 8 w-groups of 12
    const int ty  = tid >> 3;   // 32 co-groups of 4
    const int w0  = tx * 12;
    const int co0 = ty * 4;

    float acc[4][12];
    #pragma unroll
    for (int c = 0; c < 4; ++c)
        #pragma unroll
        for (int k = 0; k < 12; ++k) acc[c][k] = 0.f;

    const float* wb = wgt + (size_t)co0 * (CH*9);
    for (int ci = 0; ci < CH; ++ci) {
        // inputs: padded indices w0 .. w0+19  (output w0+k, tap t -> w0+k+t)
        float xr[20];
        #pragma unroll
        for (int j = 0; j < 5; ++j) {
            float4 v = *reinterpret_cast<const float4*>(&ld[ci][w0 + 4*j]);
            xr[4*j+0] = v.x; xr[4*j+1] = v.y; xr[4*j+2] = v.z; xr[4*j+3] = v.w;
        }
        #pragma unroll
        for (int c = 0; c < 4; ++c) {
            const float* wp = wb + (size_t)c*(CH*9) + ci*9;
            #pragma unroll
            for (int t = 0; t < 9; ++t) {
                const float wv = wp[t];
                #pragma unroll
                for (int k = 0; k < 12; ++k)
                    acc[c][k] = fmaf(wv, xr[k+t], acc[c][k]);
            }
        }
    }

    // epilogue: residual add + 2*relu, write dst
    const size_t obase = (size_t)b*CHW + (size_t)h*WW + w0;
    #pragma unroll
    for (int c = 0; c < 4; ++c) {
        const size_t o = obase + (size_t)(co0 + c)*HW;
        #pragma unroll
        for (int j = 0; j < 3; ++j) {
            float4 s = *reinterpret_cast<const float4*>(src + o + 4*j);
            float4 r;
            r.x = s.x + 2.f*fmaxf(acc[c][4*j+0], 0.f);
            r.y = s.y + 2.f*fmaxf(acc[c][4*j+1], 0.f);
            r.z = s.z + 2.f*fmaxf(acc[c][4*j+2], 0.f);
            r.w = s.w + 2.f*fmaxf(acc[c][4*j+3], 0.f);
            *reinterpret_cast<float4*>(dst + o + 4*j) = r;
        }
    }
}

// ---------------------------------------------------------------------------
// Vertical conv step (9x1 kernel along H, pad_h=4), cols rolled by woff:
//   dst[b,co,h,w] = src[b,co,h,w] + 2*relu( sum_ci sum_t wgt[co,ci,t] *
//                                           src[b,ci,h+t-4,(w+woff)%W] )
// Block: 256 threads, one block per (b, w-pair). LDS: 2 rolled cols + halo.
// ---------------------------------------------------------------------------
__global__ __launch_bounds__(256) void vconv_step(
    const float* __restrict__ src, const float* __restrict__ wgt,
    float* __restrict__ dst, int woff)
{
    __shared__ float ld[CH][2][48];  // [ci][wi][4 + 40 + 4], 49,152 B
    const int w0  = blockIdx.x * 2;
    const int b   = blockIdx.y;
    const int tid = threadIdx.x;
    const int w1  = (w0 + woff) % WW;
    const int w2  = (w0 + 1 + woff) % WW;

    const float* sb = src + (size_t)b*CHW;
    for (int idx = tid; idx < CH*HH; idx += 256) {
        int ci = idx / HH;
        int hh = idx % HH;
        const float* p = sb + (size_t)ci*HW + (size_t)hh*WW;
        ld[ci][0][4 + hh] = p[w1];
        ld[ci][1][4 + hh] = p[w2];
    }
    if (tid < CH) {
        #pragma unroll
        for (int j = 0; j < 4; ++j) {
            ld[tid][0][j] = 0.f; ld[tid][0][44 + j] = 0.f;
            ld[tid][1][j] = 0.f; ld[tid][1][44 + j] = 0.f;
        }
    }
    __syncthreads();

    const int tx  = tid & 7;
    const int ty  = tid >> 3;
    const int wi  = tx >> 2;         // which of the 2 columns
    const int h0  = (tx & 3) * 10;   // 4 h-groups of 10
    const int co0 = ty * 4;

    float acc[4][10];
    #pragma unroll
    for (int c = 0; c < 4; ++c)
        #pragma unroll
        for (int k = 0; k < 10; ++k) acc[c][k] = 0.f;

    const float* wb = wgt + (size_t)co0 * (CH*9);
    for (int ci = 0; ci < CH; ++ci) {
        float xr[18];   // padded indices h0 .. h0+17 (output h0+k, tap t)
        #pragma unroll
        for (int j = 0; j < 18; ++j) xr[j] = ld[ci][wi][h0 + j];
        #pragma unroll
        for (int c = 0; c < 4; ++c) {
            const float* wp = wb + (size_t)c*(CH*9) + ci*9;
            #pragma unroll
            for (int t = 0; t < 9; ++t) {
                const float wv = wp[t];
                #pragma unroll
                for (int k = 0; k < 10; ++k)
                    acc[c][k] = fmaf(wv, xr[k+t], acc[c][k]);
            }
        }
    }

    #pragma unroll
    for (int c = 0; c < 4; ++c) {
        const size_t o = (size_t)b*CHW + (size_t)(co0 + c)*HW
                       + (size_t)h0*WW + (w0 + wi);
        #pragma unroll
        for (int k = 0; k < 10; ++k) {
            const float s = src[o + (size_t)k*WW];
            dst[o + (size_t)k*WW] = s + 2.f*fmaxf(acc[c][k], 0.f);
        }
    }
}

// ---------------------------------------------------------------------------
// 20 sequential steps, ping-pong d_ws <-> d_out (step 19 lands in d_out).
// ---------------------------------------------------------------------------
extern "C" void kernel_launch(void* const* d_in, const int* in_sizes, int n_in,
                              void* d_out, int out_size, void* d_ws, size_t ws_size,
                              hipStream_t stream)
{
    const float* x  = (const float*)d_in[0];
    const float* wd = (const float*)d_in[1];
    const float* wu = (const float*)d_in[2];
    const float* wr = (const float*)d_in[3];
    const float* wl = (const float*)d_in[4];
    float* out = (float*)d_out;
    float* ws  = (float*)d_ws;

    const size_t WSTEP = (size_t)CH * CH * 9;
    const int hoffs[5] = {1, 2, 5, 10, 20};   // H//2^(5-i), H=40
    const int woffs[5] = {3, 6, 12, 24, 48};  // W//2^(5-i), W=96

    dim3 hgrid(HH, BB);       // 40 x 64 blocks
    dim3 vgrid(WW / 2, BB);   // 48 x 64 blocks

    const float* src = x;
    int step = 0;

    // downward: h' = (h + off) % H
    for (int i = 0; i < 5; ++i) {
        float* dst = (step & 1) ? out : ws;
        hconv_step<<<hgrid, 256, 0, stream>>>(src, wd + i*WSTEP, dst, hoffs[i]);
        src = dst; ++step;
    }
    // upward: h' = (h - off) % H  -> pass H - off
    for (int i = 0; i < 5; ++i) {
        float* dst = (step & 1) ? out : ws;
        hconv_step<<<hgrid, 256, 0, stream>>>(src, wu + i*WSTEP, dst,
                                              (HH - hoffs[i]) % HH);
        src = dst; ++step;
    }
    // rightward: w' = (w + off) % W
    for (int i = 0; i < 5; ++i) {
        float* dst = (step & 1) ? out : ws;
        vconv_step<<<vgrid, 256, 0, stream>>>(src, wr + i*WSTEP, dst, woffs[i]);
        src = dst; ++step;
    }
    // leftward: w' = (w - off) % W -> pass W - off
    for (int i = 0; i < 5; ++i) {
        float* dst = (step & 1) ? out : ws;
        vconv_step<<<vgrid, 256, 0, stream>>>(src, wl + i*WSTEP, dst,
                                              (WW - woffs[i]) % WW);
        src = dst; ++step;
    }
}

// Round 2
// 4995.165 us; speedup vs baseline: 3.7726x; 3.7726x over previous
//
#include <hip/hip_runtime.h>
#include <cstdint>
#include <cstddef>

#define CH 128
#define HH 40
#define WW 96
#define BB 64
#define HW (HH*WW)          // 3840
#define CHW ((size_t)CH*HW) // 491520

typedef _Float16 half8  __attribute__((ext_vector_type(8)));
typedef _Float16 half4v __attribute__((ext_vector_type(4)));
typedef float    float4v __attribute__((ext_vector_type(4)));

#define MFMA16(a,b,c) __builtin_amdgcn_mfma_f32_16x16x32_f16((a),(b),(c),0,0,0)

#define SPLIT_SCALE 2048.0f
#define INV_SPLIT   (1.0f/2048.0f)

#define NHWC_HALVES (BB*HH*WW*CH)   // 31,457,280 halves = 62,914,560 B
#define WSTEP_F     (CH*CH*9)       // 147,456 fp32 per step
#define WFRAG_HALVES (20*9*4*8*64*8) // 2,949,120 halves per (h|m) weight bank

// ===========================================================================
// MFMA path
// ===========================================================================

// Pre-shuffle weights into A-fragment lane order, split h/m (m scaled x2048).
// Layout: WH[((s*9+t)*4+kq)*8+mt][lane][j] ; co=mt*16+(lane&15),
// ci=kq*32+(lane>>4)*8+j.
__global__ __launch_bounds__(256) void prep_weights(
    const float* __restrict__ wd, const float* __restrict__ wu,
    const float* __restrict__ wr, const float* __restrict__ wl,
    _Float16* __restrict__ WH, _Float16* __restrict__ WM)
{
    const int bx = blockIdx.x;          // s*9 + t
    const int s = bx / 9, t = bx % 9;
    const float* src;
    if (s < 5)       src = wd + (size_t)s*WSTEP_F;
    else if (s < 10) src = wu + (size_t)(s-5)*WSTEP_F;
    else if (s < 15) src = wr + (size_t)(s-10)*WSTEP_F;
    else             src = wl + (size_t)(s-15)*WSTEP_F;

    for (int idx = threadIdx.x; idx < 2048; idx += 256) {
        const int lane = idx & 63;
        const int mt   = (idx >> 6) & 7;
        const int kq   = idx >> 9;
        const int co   = mt*16 + (lane & 15);
        const int cib  = kq*32 + (lane >> 4)*8;
        const int F    = ((((s*9 + t)*4 + kq)*8 + mt)*64 + lane)*8;
        #pragma unroll
        for (int j = 0; j < 8; ++j) {
            const float w = src[(size_t)(co*CH + (cib + j))*9 + t];
            const _Float16 h = (_Float16)w;
            WH[F + j] = h;
            WM[F + j] = (_Float16)((w - (float)h) * SPLIT_SCALE);
        }
    }
}

// fp32 NCHW -> (h,m) fp16 pair in NHWC (ci contiguous).
__global__ __launch_bounds__(256) void prep_acts(
    const float* __restrict__ x, _Float16* __restrict__ H, _Float16* __restrict__ M)
{
    __shared__ float tile[CH][33];
    const int wt = blockIdx.x, h = blockIdx.y, b = blockIdx.z;
    const int tid = threadIdx.x;
    {
        const int wl = tid & 31, c0 = tid >> 5;
        for (int it = 0; it < 16; ++it) {
            const int ci = it*8 + c0;
            tile[ci][wl] = x[((size_t)(b*CH + ci)*HH + h)*WW + wt*32 + wl];
        }
    }
    __syncthreads();
    {
        const int ci = tid & 127, w0 = tid >> 7;
        for (int it = 0; it < 16; ++it) {
            const int wl = it*2 + w0;
            const float v = tile[ci][wl];
            const _Float16 hh = (_Float16)v;
            const int o = ((b*HH + h)*WW + wt*32 + wl)*CH + ci;
            H[o] = hh;
            M[o] = (_Float16)((v - (float)hh) * SPLIT_SCALE);
        }
    }
}

// Horizontal conv (1x9 along W, pad 4), rows rolled by hoff. One block per
// (b,h): M=128 co x N=96 w, K=128 ci, 9 taps via LDS row offset.
__global__ __launch_bounds__(256, 2) void hconv_mfma(
    const _Float16* __restrict__ srcH, const _Float16* __restrict__ srcM,
    _Float16* __restrict__ dstH, _Float16* __restrict__ dstM,
    const _Float16* __restrict__ WH, const _Float16* __restrict__ WM,
    int s, int hoff)
{
    __shared__ _Float16 sB[2][104*136];   // [h|m][row 0..103][ci 0..127 pad 136]
    const int h = blockIdx.x, b = blockIdx.y;
    const int tid = threadIdx.x;
    const int hp = (h + hoff) % HH;

    {   // stage rolled row: LDS row r holds input w = r-4 (zeros in halo)
        const int l = tid & 15, r0 = tid >> 4;
        for (int it = 0; it < 7; ++it) {
            const int r = it*16 + r0;
            if (r < 104) {
                half8 vh = {}, vm = {};
                if (r >= 4 && r < 100) {
                    const int off = ((b*HH + hp)*WW + (r-4))*CH + l*8;
                    vh = *(const half8*)(srcH + off);
                    vm = *(const half8*)(srcM + off);
                }
                *(half8*)&sB[0][r*136 + l*8] = vh;
                *(half8*)&sB[1][r*136 + l*8] = vm;
            }
        }
    }
    __syncthreads();

    const int lane = tid & 63, wave = tid >> 6;
    const int n = lane & 15, quad = lane >> 4;
    const int mgrp = wave & 1, ngrp = wave >> 1;

    float4v acc0[4][3], acc1[4][3];
    #pragma unroll
    for (int i = 0; i < 4; ++i)
        #pragma unroll
        for (int j = 0; j < 3; ++j) {
            acc0[i][j] = (float4v){0.f,0.f,0.f,0.f};
            acc1[i][j] = (float4v){0.f,0.f,0.f,0.f};
        }

    int rowb[3];
    #pragma unroll
    for (int j = 0; j < 3; ++j) rowb[j] = (ngrp*3 + j)*16 + n;

    for (int t = 0; t < 9; ++t) {
        for (int kq = 0; kq < 4; ++kq) {
            const int F = ((((s*9 + t)*4 + kq)*8 + mgrp*4)*64 + lane)*8;
            half8 AH[4], AM[4];
            #pragma unroll
            for (int i = 0; i < 4; ++i) {
                AH[i] = *(const half8*)(WH + F + i*512);
                AM[i] = *(const half8*)(WM + F + i*512);
            }
            #pragma unroll
            for (int j = 0; j < 3; ++j) {
                const int ro = (rowb[j] + t)*136 + kq*32 + quad*8;
                const half8 bh = *(const half8*)&sB[0][ro];
                const half8 bm = *(const half8*)&sB[1][ro];
                #pragma unroll
                for (int i = 0; i < 4; ++i) {
                    acc0[i][j] = MFMA16(AH[i], bh, acc0[i][j]);
                    acc1[i][j] = MFMA16(AH[i], bm, acc1[i][j]);
                    acc1[i][j] = MFMA16(AM[i], bh, acc1[i][j]);
                }
            }
        }
    }

    const int spbase = (b*HH + h)*WW;
    #pragma unroll
    for (int i = 0; i < 4; ++i) {
        const int co = (mgrp*4 + i)*16 + quad*4;
        #pragma unroll
        for (int j = 0; j < 3; ++j) {
            const int w  = (ngrp*3 + j)*16 + n;
            const int sp = (spbase + w)*CH + co;
            const half4v oh = *(const half4v*)(srcH + sp);
            const half4v om = *(const half4v*)(srcM + sp);
            half4v zh, zm;
            #pragma unroll
            for (int r = 0; r < 4; ++r) {
                const float v = acc0[i][j][r] + acc1[i][j][r]*INV_SPLIT;
                const float y = (float)oh[r] + (float)om[r]*INV_SPLIT;
                const float z = y + 2.0f*fmaxf(v, 0.0f);
                const _Float16 a = (_Float16)z;
                zh[r] = a;
                zm[r] = (_Float16)((z - (float)a)*SPLIT_SCALE);
            }
            *(half4v*)(dstH + sp) = zh;
            *(half4v*)(dstM + sp) = zm;
        }
    }
}

// Vertical conv (9x1 along H, pad 4), cols rolled by woff. One block per
// (b, w-pair): 2 cols x 48 h-tile (valid 40), M=128 co.
__global__ __launch_bounds__(256, 2) void vconv_mfma(
    const _Float16* __restrict__ srcH, const _Float16* __restrict__ srcM,
    _Float16* __restrict__ dstH, _Float16* __restrict__ dstM,
    const _Float16* __restrict__ WH, const _Float16* __restrict__ WM,
    int s, int woff, int final, float* __restrict__ f32out)
{
    __shared__ _Float16 sB[2][2*56*136];  // [h|m][col*56 + row][ci pad 136]
    const int wp = blockIdx.x, b = blockIdx.y;
    const int tid = threadIdx.x;

    {   // stage 2 rolled columns; LDS row p holds input h = p-4 (zeros else)
        const int l = tid & 15, r0 = tid >> 4;
        for (int it = 0; it < 7; ++it) {
            const int r = it*16 + r0;          // 0..111
            const int col = r / 56, p = r % 56;
            half8 vh = {}, vm = {};
            if (p >= 4 && p < 44) {
                const int wsrc = (wp*2 + col + woff) % WW;
                const int off = ((b*HH + (p-4))*WW + wsrc)*CH + l*8;
                vh = *(const half8*)(srcH + off);
                vm = *(const half8*)(srcM + off);
            }
            *(half8*)&sB[0][(col*56 + p)*136 + l*8] = vh;
            *(half8*)&sB[1][(col*56 + p)*136 + l*8] = vm;
        }
    }
    __syncthreads();

    const int lane = tid & 63, wave = tid >> 6;
    const int n = lane & 15, quad = lane >> 4;
    const int mgrp = wave & 1, col = wave >> 1;

    float4v acc0[4][3], acc1[4][3];
    #pragma unroll
    for (int i = 0; i < 4; ++i)
        #pragma unroll
        for (int j = 0; j < 3; ++j) {
            acc0[i][j] = (float4v){0.f,0.f,0.f,0.f};
            acc1[i][j] = (float4v){0.f,0.f,0.f,0.f};
        }

    int rowb[3];
    #pragma unroll
    for (int j = 0; j < 3; ++j) rowb[j] = col*56 + j*16 + n;

    for (int t = 0; t < 9; ++t) {
        for (int kq = 0; kq < 4; ++kq) {
            const int F = ((((s*9 + t)*4 + kq)*8 + mgrp*4)*64 + lane)*8;
            half8 AH[4], AM[4];
            #pragma unroll
            for (int i = 0; i < 4; ++i) {
                AH[i] = *(const half8*)(WH + F + i*512);
                AM[i] = *(const half8*)(WM + F + i*512);
            }
            #pragma unroll
            for (int j = 0; j < 3; ++j) {
                const int ro = (rowb[j] + t)*136 + kq*32 + quad*8;
                const half8 bh = *(const half8*)&sB[0][ro];
                const half8 bm = *(const half8*)&sB[1][ro];
                #pragma unroll
                for (int i = 0; i < 4; ++i) {
                    acc0[i][j] = MFMA16(AH[i], bh, acc0[i][j]);
                    acc1[i][j] = MFMA16(AH[i], bm, acc1[i][j]);
                    acc1[i][j] = MFMA16(AM[i], bh, acc1[i][j]);
                }
            }
        }
    }

    const int w_out = wp*2 + col;
    #pragma unroll
    for (int i = 0; i < 4; ++i) {
        const int co = (mgrp*4 + i)*16 + quad*4;
        #pragma unroll
        for (int j = 0; j < 3; ++j) {
            const int h_out = j*16 + n;
            if (h_out < HH) {
                const int sp = ((b*HH + h_out)*WW + w_out)*CH + co;
                const half4v oh = *(const half4v*)(srcH + sp);
                const half4v om = *(const half4v*)(srcM + sp);
                if (final) {
                    float4v z4;
                    #pragma unroll
                    for (int r = 0; r < 4; ++r) {
                        const float v = acc0[i][j][r] + acc1[i][j][r]*INV_SPLIT;
                        const float y = (float)oh[r] + (float)om[r]*INV_SPLIT;
                        z4[r] = y + 2.0f*fmaxf(v, 0.0f);
                    }
                    *(float4v*)(f32out + sp) = z4;
                } else {
                    half4v zh, zm;
                    #pragma unroll
                    for (int r = 0; r < 4; ++r) {
                        const float v = acc0[i][j][r] + acc1[i][j][r]*INV_SPLIT;
                        const float y = (float)oh[r] + (float)om[r]*INV_SPLIT;
                        const float z = y + 2.0f*fmaxf(v, 0.0f);
                        const _Float16 a = (_Float16)z;
                        zh[r] = a;
                        zm[r] = (_Float16)((z - (float)a)*SPLIT_SCALE);
                    }
                    *(half4v*)(dstH + sp) = zh;
                    *(half4v*)(dstM + sp) = zm;
                }
            }
        }
    }
}

// fp32 NHWC -> fp32 NCHW (final output)
__global__ __launch_bounds__(256) void nhwc_to_nchw(
    const float* __restrict__ src, float* __restrict__ dst)
{
    __shared__ float tile[32][133];
    const int wt = blockIdx.x, h = blockIdx.y, b = blockIdx.z;
    const int tid = threadIdx.x;
    {
        const int ci = tid & 127, w0 = tid >> 7;
        for (int it = 0; it < 16; ++it) {
            const int wl = it*2 + w0;
            tile[wl][ci] = src[((size_t)(b*HH + h)*WW + wt*32 + wl)*CH + ci];
        }
    }
    __syncthreads();
    {
        const int wl = tid & 31, c0 = tid >> 5;
        for (int it = 0; it < 16; ++it) {
            const int ci = it*8 + c0;
            dst[((size_t)(b*CH + ci)*HH + h)*WW + wt*32 + wl] = tile[wl][ci];
        }
    }
}

// ===========================================================================
// Fallback fp32 vector path (round-1, proven correct) — used if ws too small.
// ===========================================================================
__global__ __launch_bounds__(256) void hconv_step(
    const float* __restrict__ src, const float* __restrict__ wgt,
    float* __restrict__ dst, int hoff)
{
    __shared__ float ld[CH][104];
    const int h = blockIdx.x, b = blockIdx.y, tid = threadIdx.x;
    const int hp = (h + hoff) % HH;
    const float* srow = src + (size_t)b*CHW + (size_t)hp*WW;
    for (int idx = tid; idx < CH*24; idx += 256) {
        int ci = idx / 24, j = idx % 24;
        float4 v = *reinterpret_cast<const float4*>(srow + (size_t)ci*HW + j*4);
        *reinterpret_cast<float4*>(&ld[ci][4 + 4*j]) = v;
    }
    if (tid < CH) {
        *reinterpret_cast<float4*>(&ld[tid][0])   = make_float4(0.f,0.f,0.f,0.f);
        *reinterpret_cast<float4*>(&ld[tid][100]) = make_float4(0.f,0.f,0.f,0.f);
    }
    __syncthreads();
    const int tx = tid & 7, ty = tid >> 3;
    const int w0 = tx*12, co0 = ty*4;
    float acc[4][12];
    #pragma unroll
    for (int c = 0; c < 4; ++c)
        #pragma unroll
        for (int k = 0; k < 12; ++k) acc[c][k] = 0.f;
    const float* wb = wgt + (size_t)co0*(CH*9);
    for (int ci = 0; ci < CH; ++ci) {
        float xr[20];
        #pragma unroll
        for (int j = 0; j < 5; ++j) {
            float4 v = *reinterpret_cast<const float4*>(&ld[ci][w0 + 4*j]);
            xr[4*j+0]=v.x; xr[4*j+1]=v.y; xr[4*j+2]=v.z; xr[4*j+3]=v.w;
        }
        #pragma unroll
        for (int c = 0; c < 4; ++c) {
            const float* wp = wb + (size_t)c*(CH*9) + ci*9;
            #pragma unroll
            for (int t = 0; t < 9; ++t) {
                const float wv = wp[t];
                #pragma unroll
                for (int k = 0; k < 12; ++k) acc[c][k] = fmaf(wv, xr[k+t], acc[c][k]);
            }
        }
    }
    const size_t obase = (size_t)b*CHW + (size_t)h*WW + w0;
    #pragma unroll
    for (int c = 0; c < 4; ++c) {
        const size_t o = obase + (size_t)(co0 + c)*HW;
        #pragma unroll
        for (int j = 0; j < 3; ++j) {
            float4 s = *reinterpret_cast<const float4*>(src + o + 4*j);
            float4 r;
            r.x = s.x + 2.f*fmaxf(acc[c][4*j+0], 0.f);
            r.y = s.y + 2.f*fmaxf(acc[c][4*j+1], 0.f);
            r.z = s.z + 2.f*fmaxf(acc[c][4*j+2], 0.f);
            r.w = s.w + 2.f*fmaxf(acc[c][4*j+3], 0.f);
            *reinterpret_cast<float4*>(dst + o + 4*j) = r;
        }
    }
}

__global__ __launch_bounds__(256) void vconv_step(
    const float* __restrict__ src, const float* __restrict__ wgt,
    float* __restrict__ dst, int woff)
{
    __shared__ float ld[CH][2][48];
    const int w0 = blockIdx.x*2, b = blockIdx.y, tid = threadIdx.x;
    const int w1 = (w0 + woff) % WW, w2 = (w0 + 1 + woff) % WW;
    const float* sb = src + (size_t)b*CHW;
    for (int idx = tid; idx < CH*HH; idx += 256) {
        int ci = idx / HH, hh = idx % HH;
        const float* p = sb + (size_t)ci*HW + (size_t)hh*WW;
        ld[ci][0][4 + hh] = p[w1];
        ld[ci][1][4 + hh] = p[w2];
    }
    if (tid < CH) {
        #pragma unroll
        for (int j = 0; j < 4; ++j) {
            ld[tid][0][j]=0.f; ld[tid][0][44+j]=0.f;
            ld[tid][1][j]=0.f; ld[tid][1][44+j]=0.f;
        }
    }
    __syncthreads();
    const int tx = tid & 7, ty = tid >> 3;
    const int wi = tx >> 2, h0 = (tx & 3)*10, co0 = ty*4;
    float acc[4][10];
    #pragma unroll
    for (int c = 0; c < 4; ++c)
        #pragma unroll
        for (int k = 0; k < 10; ++k) acc[c][k] = 0.f;
    const float* wb = wgt + (size_t)co0*(CH*9);
    for (int ci = 0; ci < CH; ++ci) {
        float xr[18];
        #pragma unroll
        for (int j = 0; j < 18; ++j) xr[j] = ld[ci][wi][h0 + j];
        #pragma unroll
        for (int c = 0; c < 4; ++c) {
            const float* wp = wb + (size_t)c*(CH*9) + ci*9;
            #pragma unroll
            for (int t = 0; t < 9; ++t) {
                const float wv = wp[t];
                #pragma unroll
                for (int k = 0; k < 10; ++k) acc[c][k] = fmaf(wv, xr[k+t], acc[c][k]);
            }
        }
    }
    #pragma unroll
    for (int c = 0; c < 4; ++c) {
        const size_t o = (size_t)b*CHW + (size_t)(co0 + c)*HW + (size_t)h0*WW + (w0 + wi);
        #pragma unroll
        for (int k = 0; k < 10; ++k) {
            const float s = src[o + (size_t)k*WW];
            dst[o + (size_t)k*WW] = s + 2.f*fmaxf(acc[c][k], 0.f);
        }
    }
}

// ===========================================================================
extern "C" void kernel_launch(void* const* d_in, const int* in_sizes, int n_in,
                              void* d_out, int out_size, void* d_ws, size_t ws_size,
                              hipStream_t stream)
{
    const float* x  = (const float*)d_in[0];
    const float* wd = (const float*)d_in[1];
    const float* wu = (const float*)d_in[2];
    const float* wr = (const float*)d_in[3];
    const float* wl = (const float*)d_in[4];

    const size_t NEED = 125829120ULL + 2ULL*WFRAG_HALVES*2ULL;  // 137,625,600 B

    if (ws_size >= NEED) {
        _Float16* HA  = (_Float16*)d_ws;
        _Float16* MA  = HA + NHWC_HALVES;
        _Float16* WHp = (_Float16*)((char*)d_ws + 125829120ULL);
        _Float16* WMp = WHp + WFRAG_HALVES;
        _Float16* HB  = (_Float16*)d_out;
        _Float16* MB  = HB + NHWC_HALVES;
        float* f32tmp = (float*)d_ws;   // reuses the A-pair region (dead by then)

        prep_weights<<<dim3(180), 256, 0, stream>>>(wd, wu, wr, wl, WHp, WMp);
        prep_acts<<<dim3(3, HH, BB), 256, 0, stream>>>(x, HA, MA);

        const int hoffs[10] = {1,2,5,10,20, 39,38,35,30,20};     // wd: +off, wu: H-off
        for (int s = 0; s < 10; ++s) {
            const _Float16* sH = (s & 1) ? HB : HA;
            const _Float16* sM = (s & 1) ? MB : MA;
            _Float16* dH = (s & 1) ? HA : HB;
            _Float16* dM = (s & 1) ? MA : MB;
            hconv_mfma<<<dim3(HH, BB), 256, 0, stream>>>(sH, sM, dH, dM,
                                                         WHp, WMp, s, hoffs[s]);
        }
        const int woffs[10] = {3,6,12,24,48, 93,90,84,72,48};    // wr: +off, wl: W-off
        for (int k = 0; k < 10; ++k) {
            const int s = 10 + k;
            const _Float16* sH = (s & 1) ? HB : HA;
            const _Float16* sM = (s & 1) ? MB : MA;
            _Float16* dH = (s & 1) ? HA : HB;
            _Float16* dM = (s & 1) ? MA : MB;
            const int fin = (s == 19);
            vconv_mfma<<<dim3(WW/2, BB), 256, 0, stream>>>(sH, sM, dH, dM,
                                                           WHp, WMp, s, woffs[k],
                                                           fin, f32tmp);
        }
        nhwc_to_nchw<<<dim3(3, HH, BB), 256, 0, stream>>>(f32tmp, (float*)d_out);
    } else {
        // fp32 fallback (round-1 path)
        float* out = (float*)d_out;
        float* ws  = (float*)d_ws;
        const size_t WSTEP = (size_t)WSTEP_F;
        const int hoffs[5] = {1, 2, 5, 10, 20};
        const int woffs[5] = {3, 6, 12, 24, 48};
        dim3 hgrid(HH, BB), vgrid(WW/2, BB);
        const float* src = x;
        int step = 0;
        for (int i = 0; i < 5; ++i) {
            float* dst = (step & 1) ? out : ws;
            hconv_step<<<hgrid, 256, 0, stream>>>(src, wd + i*WSTEP, dst, hoffs[i]);
            src = dst; ++step;
        }
        for (int i = 0; i < 5; ++i) {
            float* dst = (step & 1) ? out : ws;
            hconv_step<<<hgrid, 256, 0, stream>>>(src, wu + i*WSTEP, dst, (HH - hoffs[i]) % HH);
            src = dst; ++step;
        }
        for (int i = 0; i < 5; ++i) {
            float* dst = (step & 1) ? out : ws;
            vconv_step<<<vgrid, 256, 0, stream>>>(src, wr + i*WSTEP, dst, woffs[i]);
            src = dst; ++step;
        }
        for (int i = 0; i < 5; ++i) {
            float* dst = (step & 1) ? out : ws;
            vconv_step<<<vgrid, 256, 0, stream>>>(src, wl + i*WSTEP, dst, (WW - woffs[i]) % WW);
            src = dst; ++step;
        }
    }
}